// Round 1
// baseline (206.003 us; speedup 1.0000x reference)
//
#include <hip/hip_runtime.h>

#define BB 8
#define SS 4096
#define DD 768
#define EE 128
#define PP 8128   // E*(E-1)/2
#define MP 25
#define MT 3500
#define D4 192    // DD/4

// ---------------------------------------------------------------------------
// Kernel 1: per-batch special-token scan (wave-0 ballot scan over S=4096),
// then gather prompt embeddings (25 rows x 768 f32) + write prompt mask.
// ---------------------------------------------------------------------------
__global__ void k_prompts(const float* __restrict__ te, const int* __restrict__ ids,
                          float* __restrict__ out0, float* __restrict__ out1) {
    int b = blockIdx.x;
    __shared__ int pos[MP];
    __shared__ int nspec_s;
    int t = threadIdx.x;
    if (t < MP) pos[t] = -1;
    __syncthreads();
    if (t < 64) {
        int lane = t;
        int base = 0;
        const int* row = ids + b * SS;
        for (int chunk = 0; chunk < SS; chunk += 64) {
            bool isSpec = (row[chunk + lane] == 1);
            unsigned long long m = __ballot(isSpec);
            if (isSpec) {
                int slot = base + __popcll(m & ((1ull << lane) - 1ull));
                if (slot < MP) pos[slot] = chunk + lane;
            }
            base += __popcll(m);
        }
        if (lane == 0) nspec_s = base;
    }
    __syncthreads();
    int nspec = nspec_s;
    if (t < MP) out1[b * MP + t] = (t < nspec) ? 1.0f : 0.0f;
    const float4* te4 = (const float4*)te;
    float4* o4 = (float4*)out0;
    for (int idx = t; idx < MP * D4; idx += blockDim.x) {
        int j = idx / D4, e = idx - j * D4;
        int src = pos[j];
        float4 v = make_float4(0.f, 0.f, 0.f, 0.f);
        if (src >= 0) v = te4[((size_t)(b * SS + src)) * D4 + e];
        o4[((size_t)(b * MP + j)) * D4 + e] = v;
    }
}

// ---------------------------------------------------------------------------
// Kernel 2: init word->source map to -1, write word_mask output.
// ---------------------------------------------------------------------------
__global__ void k_words_init(int* __restrict__ wordpos, float* __restrict__ out3,
                             const int* __restrict__ tlen) {
    int i = blockIdx.x * blockDim.x + threadIdx.x;
    if (i >= BB * MT) return;
    int b = i / MT, w = i - b * MT;
    wordpos[i] = -1;
    out3[i] = (w < tlen[b]) ? 1.0f : 0.0f;
}

// ---------------------------------------------------------------------------
// Kernel 3: scatter source position s into wordpos[b][words_mask-1].
// (word indices are unique per batch -> plain store, no atomics)
// ---------------------------------------------------------------------------
__global__ void k_words_scatter(const int* __restrict__ wm, int* __restrict__ wordpos) {
    int i = blockIdx.x * blockDim.x + threadIdx.x;
    if (i >= BB * SS) return;
    int b = i / SS;
    int v = wm[i];
    if (v > 0 && v <= MT) wordpos[b * MT + v - 1] = i - b * SS;
}

// ---------------------------------------------------------------------------
// Kernel 4: per-batch stable partition of the 8128 triu pairs.
// 1024 threads x 8 contiguous pairs each; block exclusive scan of sel-counts.
// Writes pair_idx (as floats), pair_mask, and head/tail entity indices (ws).
// ---------------------------------------------------------------------------
__global__ __launch_bounds__(1024) void k_pairs(const float* __restrict__ adj,
                                                float* __restrict__ out4,
                                                float* __restrict__ out5,
                                                int* __restrict__ hsrc,
                                                int* __restrict__ tsrc) {
    int b = blockIdx.x;
    int t = threadIdx.x;
    __shared__ int cnt[1024];
    __shared__ int totalK;
    int r8[8], c8[8];
    bool s8[8];
    int my = 0;
    for (int i = 0; i < 8; ++i) {
        int p = t * 8 + i;
        r8[i] = 0; c8[i] = 0; s8[i] = false;
        if (p < PP) {
            // find r = max r with start(r) <= p, start(r) = r*(255-r)/2
            int lo = 0, hi = EE - 2;
            while (lo < hi) {
                int mid = (lo + hi + 1) >> 1;
                int st = mid * (2 * EE - 1 - mid) / 2;
                if (st <= p) lo = mid; else hi = mid - 1;
            }
            int r = lo;
            int st = r * (2 * EE - 1 - r) / 2;
            int c = r + 1 + (p - st);
            r8[i] = r; c8[i] = c;
            float v = adj[((size_t)b * EE + r) * EE + c];
            bool s = v > 0.5f;
            s8[i] = s;
            my += s ? 1 : 0;
        }
    }
    cnt[t] = my;
    __syncthreads();
    // Hillis-Steele inclusive scan over 1024 entries
    for (int off = 1; off < 1024; off <<= 1) {
        int v = cnt[t];
        int add = (t >= off) ? cnt[t - off] : 0;
        __syncthreads();
        cnt[t] = v + add;
        __syncthreads();
    }
    if (t == 1023) totalK = cnt[1023];
    __syncthreads();
    int K = totalK;
    int selb = (t == 0) ? 0 : cnt[t - 1];
    for (int i = 0; i < 8; ++i) {
        int p = t * 8 + i;
        if (p >= PP) break;
        int q;
        if (s8[i]) { q = selb; ++selb; }
        else       { q = K + (p - selb); }
        size_t oq = (size_t)b * PP + q;
        out4[oq * 2 + 0] = s8[i] ? (float)r8[i] : -1.0f;
        out4[oq * 2 + 1] = s8[i] ? (float)c8[i] : -1.0f;
        out5[oq] = s8[i] ? 1.0f : 0.0f;
        hsrc[oq] = s8[i] ? r8[i] : 0;
        tsrc[oq] = s8[i] ? c8[i] : 0;
    }
}

// ---------------------------------------------------------------------------
// Kernel 5: words_embedding gather — one block (192 thr) per output row.
// ---------------------------------------------------------------------------
__global__ void k_words_gather(const float* __restrict__ te, const int* __restrict__ wordpos,
                               float* __restrict__ out2) {
    int row = blockIdx.x;      // b*MT + w
    int b = row / MT;
    int src = wordpos[row];
    int t = threadIdx.x;       // 0..191
    const float4* te4 = (const float4*)te;
    float4* o4 = (float4*)out2;
    float4 v = make_float4(0.f, 0.f, 0.f, 0.f);
    if (src >= 0) v = te4[((size_t)(b * SS + src)) * D4 + t];
    o4[(size_t)row * D4 + t] = v;
}

// ---------------------------------------------------------------------------
// Kernel 6: head_rep / tail_rep gather from span_rep (L2-resident, 3 MB).
// ---------------------------------------------------------------------------
__global__ void k_pair_gather(const float* __restrict__ sr, const int* __restrict__ hsrc,
                              const int* __restrict__ tsrc,
                              float* __restrict__ out6, float* __restrict__ out7) {
    int row = blockIdx.x;      // 0 .. 2*B*P
    int t = threadIdx.x;       // 0..191
    const float4* sr4 = (const float4*)sr;
    int half = BB * PP;
    bool isHead = row < half;
    int idx = isHead ? row : row - half;
    int b = idx / PP;
    int src = isHead ? hsrc[idx] : tsrc[idx];
    float4 v = sr4[((size_t)(b * EE + src)) * D4 + t];
    float4* o4 = (float4*)(isHead ? out6 : out7);
    o4[(size_t)idx * D4 + t] = v;
}

extern "C" void kernel_launch(void* const* d_in, const int* in_sizes, int n_in,
                              void* d_out, int out_size, void* d_ws, size_t ws_size,
                              hipStream_t stream) {
    const float* te   = (const float*)d_in[0];  // token_embeds (B,S,D)
    const float* adj  = (const float*)d_in[1];  // adj (B,E,E)
    const float* sr   = (const float*)d_in[2];  // span_rep (B,E,D)
    const int*   ids  = (const int*)d_in[3];    // input_ids (B,S)
    // d_in[4] attention_mask: unused by the reference outputs
    const int*   tlen = (const int*)d_in[5];    // text_lengths (B,1)
    const int*   wm   = (const int*)d_in[6];    // words_mask (B,S)
    float* out = (float*)d_out;

    size_t off0 = 0;
    size_t off1 = off0 + (size_t)BB * MP * DD;   // prompts_embedding
    size_t off2 = off1 + (size_t)BB * MP;        // prompts_mask
    size_t off3 = off2 + (size_t)BB * MT * DD;   // words_embedding
    size_t off4 = off3 + (size_t)BB * MT;        // word_mask
    size_t off5 = off4 + (size_t)BB * PP * 2;    // pair_idx
    size_t off6 = off5 + (size_t)BB * PP;        // pair_mask
    size_t off7 = off6 + (size_t)BB * PP * DD;   // head_rep -> tail_rep

    int* wordpos = (int*)d_ws;               // B*MT
    int* hsrc = wordpos + BB * MT;           // B*PP
    int* tsrc = hsrc + BB * PP;              // B*PP

    k_prompts<<<BB, 256, 0, stream>>>(te, ids, out + off0, out + off1);
    k_words_init<<<(BB * MT + 255) / 256, 256, 0, stream>>>(wordpos, out + off3, tlen);
    k_words_scatter<<<(BB * SS + 255) / 256, 256, 0, stream>>>(wm, wordpos);
    k_pairs<<<BB, 1024, 0, stream>>>(adj, out + off4, out + off5, hsrc, tsrc);
    k_words_gather<<<BB * MT, 192, 0, stream>>>(te, wordpos, out + off2);
    k_pair_gather<<<2 * BB * PP, 192, 0, stream>>>(sr, hsrc, tsrc, out + off6, out + off7);
}

// Round 2
// 160.177 us; speedup vs baseline: 1.2861x; 1.2861x over previous
//
#include <hip/hip_runtime.h>

#define BB 8
#define SS 4096
#define DD 768
#define EE 128
#define PP 8128   // E*(E-1)/2
#define MP 25
#define MT 3500
#define D4 192    // DD/4 float4 per row
#define NROWS_W (BB*MT)              // 28000 words rows
#define NROWS_P (BB*PP)              // 65024 pair rows (per head/tail)
#define R_TOTAL (NROWS_W + 2*NROWS_P) // 158048 total gather rows

typedef float f32x4 __attribute__((ext_vector_type(4)));

// ---------------------------------------------------------------------------
// Kernel A: one block per batch (1024 thr). Fuses:
//   - special-token scan (16-wave parallel ballot scan) + prompt gather + mask
//   - word_mask output + wordpos init + scatter (block-local dependency)
//   - pair stable-partition (shfl wave scan + cross-wave combine)
// ---------------------------------------------------------------------------
__global__ __launch_bounds__(1024) void k_prep(
    const float* __restrict__ te, const int* __restrict__ ids,
    const float* __restrict__ adj, const int* __restrict__ wm,
    const int* __restrict__ tlen,
    float* __restrict__ out0, float* __restrict__ out1,
    float* __restrict__ out3, float* __restrict__ out4, float* __restrict__ out5,
    int* __restrict__ wordpos, int* __restrict__ hsrc, int* __restrict__ tsrc)
{
    int b = blockIdx.x;
    int t = threadIdx.x, wave = t >> 6, lane = t & 63;
    __shared__ int pos[MP];
    __shared__ int spos[16 * 32];
    __shared__ int wcnt[16];
    __shared__ int woff[17];
    __shared__ int wsum[16];

    if (t < MP) pos[t] = -1;

    // --- specials scan: wave w covers tokens [w*256, (w+1)*256) ---
    {
        const int* row = ids + b * SS;
        int base = 0;
        for (int c = 0; c < 4; ++c) {
            int p = wave * 256 + c * 64 + lane;
            bool s = (row[p] == 1);
            unsigned long long m = __ballot(s);
            if (s) {
                int sl = base + __popcll(m & ((1ull << lane) - 1ull));
                if (sl < 32) spos[wave * 32 + sl] = p;
            }
            base += __popcll(m);
        }
        if (lane == 0) wcnt[wave] = base;
    }
    __syncthreads();
    if (t == 0) {
        int acc = 0;
        for (int w = 0; w < 16; ++w) { woff[w] = acc; acc += wcnt[w]; }
        woff[16] = acc;
    }
    __syncthreads();
    {
        int cnt = wcnt[wave]; if (cnt > 32) cnt = 32;
        if (lane < cnt) {
            int g = woff[wave] + lane;
            if (g < MP) pos[g] = spos[wave * 32 + lane];
        }
    }

    // --- word_mask output + wordpos init ---
    int L = tlen[b];
    for (int i = t; i < MT; i += 1024) {
        out3[b * MT + i] = (i < L) ? 1.0f : 0.0f;
        wordpos[b * MT + i] = -1;
    }
    __syncthreads();   // pos[] final; wordpos init done before scatter

    // --- words scatter (unique targets -> plain store) ---
    for (int i = t; i < SS; i += 1024) {
        int v = wm[b * SS + i];
        if (v > 0 && v <= MT) wordpos[b * MT + v - 1] = i;
    }

    // --- prompts mask + gather (25 rows x 192 f4) ---
    int nspec = woff[16];
    if (t < MP) out1[b * MP + t] = (t < nspec) ? 1.0f : 0.0f;
    {
        const f32x4* te4 = (const f32x4*)te;
        f32x4* o4 = (f32x4*)out0;
        for (int idx = t; idx < MP * D4; idx += 1024) {
            int j = idx / D4, e = idx - j * D4;
            int src = pos[j];
            f32x4 v = (f32x4)(0.0f);
            if (src >= 0) v = te4[((size_t)(b * SS + src)) * D4 + e];
            o4[((size_t)(b * MP + j)) * D4 + e] = v;
        }
    }

    // --- pair stable-partition: 8 contiguous pairs / thread ---
    int r8[8], c8[8]; bool s8[8]; int my = 0;
    for (int i = 0; i < 8; ++i) {
        int p = t * 8 + i;
        r8[i] = 0; c8[i] = 0; s8[i] = false;
        if (p < PP) {
            int lo = 0, hi = EE - 2;
            while (lo < hi) {
                int mid = (lo + hi + 1) >> 1;
                int st = mid * (2 * EE - 1 - mid) / 2;
                if (st <= p) lo = mid; else hi = mid - 1;
            }
            int r = lo;
            int st = r * (2 * EE - 1 - r) / 2;
            int c = r + 1 + (p - st);
            r8[i] = r; c8[i] = c;
            s8[i] = adj[((size_t)b * EE + r) * EE + c] > 0.5f;
            my += s8[i] ? 1 : 0;
        }
    }
    // wave inclusive scan of per-thread counts
    int inc = my;
    for (int off = 1; off < 64; off <<= 1) {
        int n = __shfl_up(inc, off);
        if (lane >= off) inc += n;
    }
    if (lane == 63) wsum[wave] = inc;
    __syncthreads();
    int wv_off = 0, K = 0;
    for (int w = 0; w < 16; ++w) {
        int s = wsum[w];
        if (w < wave) wv_off += s;
        K += s;
    }
    int selb = wv_off + inc - my;   // selected-before for my first pair
    for (int i = 0; i < 8; ++i) {
        int p = t * 8 + i;
        if (p >= PP) break;
        int q;
        if (s8[i]) { q = selb; ++selb; }
        else       { q = K + (p - selb); }
        size_t oq = (size_t)b * PP + q;
        out4[oq * 2 + 0] = s8[i] ? (float)r8[i] : -1.0f;
        out4[oq * 2 + 1] = s8[i] ? (float)c8[i] : -1.0f;
        out5[oq]         = s8[i] ? 1.0f : 0.0f;
        hsrc[oq]         = s8[i] ? r8[i] : 0;
        tsrc[oq]         = s8[i] ? c8[i] : 0;
    }
}

// ---------------------------------------------------------------------------
// Kernel B: unified gather. Grid-stride, one 768-f32 row per 64-lane wave per
// iteration (3 x float4 per lane). Rows: [0,28000) words_embedding,
// [28000,93024) head_rep, [93024,158048) tail_rep. Nontemporal stores.
// ---------------------------------------------------------------------------
__global__ __launch_bounds__(256) void k_gather(
    const float* __restrict__ te, const float* __restrict__ sr,
    const int* __restrict__ wordpos, const int* __restrict__ hsrc,
    const int* __restrict__ tsrc,
    float* __restrict__ out2, float* __restrict__ out6, float* __restrict__ out7)
{
    int gw = blockIdx.x * 4 + (threadIdx.x >> 6);
    int lane = threadIdx.x & 63;
    int nw = gridDim.x * 4;
    const f32x4* te4 = (const f32x4*)te;
    const f32x4* sr4 = (const f32x4*)sr;
    for (int row = gw; row < R_TOTAL; row += nw) {
        const f32x4* src4;
        f32x4* dst4;
        bool valid = true;
        bool stream_src = false;
        if (row < NROWS_W) {
            int b = row / MT;
            int s = wordpos[row];
            valid = (s >= 0);
            src4 = te4 + ((size_t)(b * SS + s)) * D4;
            dst4 = (f32x4*)out2 + (size_t)row * D4;
            stream_src = true;           // te rows are read-once
        } else {
            int idx2 = row - NROWS_W;
            bool head = idx2 < NROWS_P;
            int idx = head ? idx2 : idx2 - NROWS_P;
            int b = idx / PP;
            int s = head ? hsrc[idx] : tsrc[idx];
            src4 = sr4 + ((size_t)(b * EE + s)) * D4;
            dst4 = (f32x4*)(head ? out6 : out7) + (size_t)idx * D4;
        }
        #pragma unroll
        for (int k = 0; k < 3; ++k) {
            f32x4 v;
            if (valid) {
                v = stream_src ? __builtin_nontemporal_load(&src4[lane + 64 * k])
                               : src4[lane + 64 * k];
            } else {
                v = (f32x4)(0.0f);
            }
            __builtin_nontemporal_store(v, &dst4[lane + 64 * k]);
        }
    }
}

extern "C" void kernel_launch(void* const* d_in, const int* in_sizes, int n_in,
                              void* d_out, int out_size, void* d_ws, size_t ws_size,
                              hipStream_t stream) {
    const float* te   = (const float*)d_in[0];  // token_embeds (B,S,D)
    const float* adj  = (const float*)d_in[1];  // adj (B,E,E)
    const float* sr   = (const float*)d_in[2];  // span_rep (B,E,D)
    const int*   ids  = (const int*)d_in[3];    // input_ids (B,S)
    // d_in[4] attention_mask: unused
    const int*   tlen = (const int*)d_in[5];    // text_lengths (B,1)
    const int*   wm   = (const int*)d_in[6];    // words_mask (B,S)
    float* out = (float*)d_out;

    size_t off0 = 0;
    size_t off1 = off0 + (size_t)BB * MP * DD;   // prompts_embedding
    size_t off2 = off1 + (size_t)BB * MP;        // prompts_mask
    size_t off3 = off2 + (size_t)BB * MT * DD;   // words_embedding
    size_t off4 = off3 + (size_t)BB * MT;        // word_mask
    size_t off5 = off4 + (size_t)BB * PP * 2;    // pair_idx
    size_t off6 = off5 + (size_t)BB * PP;        // pair_mask
    size_t off7 = off6 + (size_t)BB * PP * DD;   // head_rep -> tail_rep

    int* wordpos = (int*)d_ws;               // B*MT
    int* hsrc = wordpos + BB * MT;           // B*PP
    int* tsrc = hsrc + BB * PP;              // B*PP

    k_prep<<<BB, 1024, 0, stream>>>(te, ids, adj, wm, tlen,
                                    out + off0, out + off1, out + off3,
                                    out + off4, out + off5,
                                    wordpos, hsrc, tsrc);
    k_gather<<<2048, 256, 0, stream>>>(te, sr, wordpos, hsrc, tsrc,
                                       out + off2, out + off6, out + off7);
}

// Round 3
// 150.378 us; speedup vs baseline: 1.3699x; 1.0652x over previous
//
#include <hip/hip_runtime.h>

#define BB 8
#define SS 4096
#define DD 768
#define EE 128
#define PP 8128   // E*(E-1)/2
#define MP 25
#define MT 3500
#define D4 192    // DD/4 float4 per row
#define NROWS_W  (BB*MT)   // 28000 words rows
#define NROWS_P  (BB*PP)   // 65024 pair rows (per head/tail)
#define NROWS_PR (BB*MP)   // 200 prompt rows
#define R_TOTAL  (NROWS_W + 2*NROWS_P + NROWS_PR)  // 158248

typedef float f32x4 __attribute__((ext_vector_type(4)));

// ---------------------------------------------------------------------------
// Kernel A (tiny, 8 blocks x 1024): index production ONLY.
//   - specials ballot-scan -> ws.pos[b][25], ws.nspec[b]
//   - word_mask output + wordpos init + scatter
//   - pair stable-partition -> ws.pairrec[b][q] packed (sel<<31 | r<<8 | c)
// No token_embeds access, no wide output writes.
// ---------------------------------------------------------------------------
__global__ __launch_bounds__(1024) void k_prep(
    const int* __restrict__ ids, const float* __restrict__ adj,
    const int* __restrict__ wm, const int* __restrict__ tlen,
    float* __restrict__ out3,
    int* __restrict__ wordpos, int* __restrict__ pairrec,
    int* __restrict__ pos, int* __restrict__ nspec)
{
    int b = blockIdx.x;
    int t = threadIdx.x, wave = t >> 6, lane = t & 63;
    __shared__ int pos_s[MP];
    __shared__ int spos[16 * 32];
    __shared__ int wcnt[16];
    __shared__ int woff[17];
    __shared__ int wsum[16];

    if (t < MP) pos_s[t] = -1;

    // --- specials scan: wave w covers tokens [w*256,(w+1)*256) ---
    {
        const int* row = ids + b * SS;
        int base = 0;
        for (int c = 0; c < 4; ++c) {
            int p = wave * 256 + c * 64 + lane;
            bool s = (row[p] == 1);
            unsigned long long m = __ballot(s);
            if (s) {
                int sl = base + __popcll(m & ((1ull << lane) - 1ull));
                if (sl < 32) spos[wave * 32 + sl] = p;
            }
            base += __popcll(m);
        }
        if (lane == 0) wcnt[wave] = base;
    }
    __syncthreads();
    if (t == 0) {
        int acc = 0;
        for (int w = 0; w < 16; ++w) { woff[w] = acc; acc += wcnt[w]; }
        woff[16] = acc;
    }
    __syncthreads();
    {
        int cnt = wcnt[wave]; if (cnt > 32) cnt = 32;
        if (lane < cnt) {
            int g = woff[wave] + lane;
            if (g < MP) pos_s[g] = spos[wave * 32 + lane];
        }
    }

    // --- word_mask output + wordpos init ---
    int L = tlen[b];
    for (int i = t; i < MT; i += 1024) {
        out3[b * MT + i] = (i < L) ? 1.0f : 0.0f;
        wordpos[b * MT + i] = -1;
    }
    __syncthreads();   // pos_s final; wordpos init done before scatter

    // --- words scatter (unique targets -> plain store) + export pos/nspec ---
    for (int i = t; i < SS; i += 1024) {
        int v = wm[b * SS + i];
        if (v > 0 && v <= MT) wordpos[b * MT + v - 1] = i;
    }
    if (t < MP) pos[b * MP + t] = pos_s[t];
    if (t == 0) nspec[b] = woff[16];

    // --- pair stable-partition: 8 contiguous pairs / thread ---
    int r8[8], c8[8]; bool s8[8]; int my = 0;
    for (int i = 0; i < 8; ++i) {
        int p = t * 8 + i;
        r8[i] = 0; c8[i] = 0; s8[i] = false;
        if (p < PP) {
            int lo = 0, hi = EE - 2;
            while (lo < hi) {
                int mid = (lo + hi + 1) >> 1;
                int st = mid * (2 * EE - 1 - mid) / 2;
                if (st <= p) lo = mid; else hi = mid - 1;
            }
            int r = lo;
            int st = r * (2 * EE - 1 - r) / 2;
            int c = r + 1 + (p - st);
            r8[i] = r; c8[i] = c;
            s8[i] = adj[((size_t)b * EE + r) * EE + c] > 0.5f;
            my += s8[i] ? 1 : 0;
        }
    }
    int inc = my;
    for (int off = 1; off < 64; off <<= 1) {
        int n = __shfl_up(inc, off);
        if (lane >= off) inc += n;
    }
    if (lane == 63) wsum[wave] = inc;
    __syncthreads();
    int wv_off = 0, K = 0;
    for (int w = 0; w < 16; ++w) {
        int s = wsum[w];
        if (w < wave) wv_off += s;
        K += s;
    }
    int selb = wv_off + inc - my;
    for (int i = 0; i < 8; ++i) {
        int p = t * 8 + i;
        if (p >= PP) break;
        int q;
        if (s8[i]) { q = selb; ++selb; }
        else       { q = K + (p - selb); }
        unsigned rec = s8[i] ? (0x80000000u | ((unsigned)r8[i] << 8) | (unsigned)c8[i]) : 0u;
        pairrec[(size_t)b * PP + q] = (int)rec;
    }
}

// ---------------------------------------------------------------------------
// Kernel B: unified gather, one 768-f32 row per wave per iteration.
// Row space: [0,28000) words | [28000,93024) head | [93024,158048) tail |
//            [158048,158248) prompts. Lane 0 of head rows writes
// pair_idx/pair_mask; lane 0 of prompt rows writes prompt mask.
// PLAIN stores (match fill-kernel 6.9 TB/s evidence); nt loads on te only.
// ---------------------------------------------------------------------------
__global__ __launch_bounds__(256) void k_gather(
    const float* __restrict__ te, const float* __restrict__ sr,
    const int* __restrict__ wordpos, const int* __restrict__ pairrec,
    const int* __restrict__ pos, const int* __restrict__ nspec,
    float* __restrict__ out0, float* __restrict__ out1, float* __restrict__ out2,
    float* __restrict__ out4, float* __restrict__ out5,
    float* __restrict__ out6, float* __restrict__ out7)
{
    int gw = blockIdx.x * 4 + (threadIdx.x >> 6);
    int lane = threadIdx.x & 63;
    int nw = gridDim.x * 4;
    const f32x4* te4 = (const f32x4*)te;
    const f32x4* sr4 = (const f32x4*)sr;
    for (int row = gw; row < R_TOTAL; row += nw) {
        const f32x4* src4;
        f32x4* dst4;
        bool valid = true;
        bool stream_src = false;
        if (row < NROWS_W) {
            int b = row / MT;
            int s = wordpos[row];
            valid = (s >= 0);
            src4 = te4 + ((size_t)(b * SS + s)) * D4;
            dst4 = (f32x4*)out2 + (size_t)row * D4;
            stream_src = true;
        } else if (row < NROWS_W + 2 * NROWS_P) {
            int idx2 = row - NROWS_W;
            bool head = idx2 < NROWS_P;
            int idx = head ? idx2 : idx2 - NROWS_P;
            int b = idx / PP;
            unsigned rec = (unsigned)pairrec[idx];
            int r = (rec >> 8) & 0x7F;
            int c = rec & 0xFF;
            int s = head ? r : c;      // rec==0 (unselected) -> row 0, matches ref
            src4 = sr4 + ((size_t)(b * EE + s)) * D4;
            dst4 = (f32x4*)(head ? out6 : out7) + (size_t)idx * D4;
            if (head && lane == 0) {
                bool sel = rec != 0u;
                out4[(size_t)idx * 2 + 0] = sel ? (float)r : -1.0f;
                out4[(size_t)idx * 2 + 1] = sel ? (float)c : -1.0f;
                out5[idx] = sel ? 1.0f : 0.0f;
            }
        } else {
            int j2 = row - (NROWS_W + 2 * NROWS_P);
            int b = j2 / MP;
            int j = j2 - b * MP;
            int s = pos[j2];
            valid = (s >= 0);
            src4 = te4 + ((size_t)(b * SS + s)) * D4;
            dst4 = (f32x4*)out0 + (size_t)j2 * D4;
            stream_src = true;
            if (lane == 0) out1[j2] = (j < nspec[b]) ? 1.0f : 0.0f;
        }
        #pragma unroll
        for (int k = 0; k < 3; ++k) {
            f32x4 v = (f32x4)(0.0f);
            if (valid) {
                v = stream_src ? __builtin_nontemporal_load(&src4[lane + 64 * k])
                               : src4[lane + 64 * k];
            }
            dst4[lane + 64 * k] = v;   // plain store
        }
    }
}

extern "C" void kernel_launch(void* const* d_in, const int* in_sizes, int n_in,
                              void* d_out, int out_size, void* d_ws, size_t ws_size,
                              hipStream_t stream) {
    const float* te   = (const float*)d_in[0];  // token_embeds (B,S,D)
    const float* adj  = (const float*)d_in[1];  // adj (B,E,E)
    const float* sr   = (const float*)d_in[2];  // span_rep (B,E,D)
    const int*   ids  = (const int*)d_in[3];    // input_ids (B,S)
    // d_in[4] attention_mask: unused
    const int*   tlen = (const int*)d_in[5];    // text_lengths (B,1)
    const int*   wm   = (const int*)d_in[6];    // words_mask (B,S)
    float* out = (float*)d_out;

    size_t off0 = 0;
    size_t off1 = off0 + (size_t)BB * MP * DD;   // prompts_embedding
    size_t off2 = off1 + (size_t)BB * MP;        // prompts_mask
    size_t off3 = off2 + (size_t)BB * MT * DD;   // words_embedding
    size_t off4 = off3 + (size_t)BB * MT;        // word_mask
    size_t off5 = off4 + (size_t)BB * PP * 2;    // pair_idx
    size_t off6 = off5 + (size_t)BB * PP;        // pair_mask
    size_t off7 = off6 + (size_t)BB * PP * DD;   // head_rep -> tail_rep

    int* wordpos = (int*)d_ws;                   // B*MT
    int* pairrec = wordpos + BB * MT;            // B*PP
    int* pos     = pairrec + BB * PP;            // B*MP
    int* nspec   = pos + BB * MP;                // B

    k_prep<<<BB, 1024, 0, stream>>>(ids, adj, wm, tlen, out + off3,
                                    wordpos, pairrec, pos, nspec);
    k_gather<<<2048, 256, 0, stream>>>(te, sr, wordpos, pairrec, pos, nspec,
                                       out + off0, out + off1, out + off2,
                                       out + off4, out + off5,
                                       out + off6, out + off7);
}